// Round 3
// baseline (1375.134 us; speedup 1.0000x reference)
//
#include <hip/hip_runtime.h>
#include <math.h>

// SGC: out = log_softmax( S^3 * x * (W1*W2*W3) )
// Edges bucketed by dst>>7 (128 nodes/bucket); aggregation = block-per-bucket
// LDS tile accumulate. No exact per-node CSR (kills the 16x write-amp fill).

#define BW   128      // nodes per bucket
#define NBMAX 1024    // max buckets (N <= 131072)
#define D    40

// ---------- tiny weight-collapse GEMMs ----------
__global__ void k_w12(const float* __restrict__ W1, const float* __restrict__ W2,
                      float* __restrict__ W12) {
    int idx = blockIdx.x * blockDim.x + threadIdx.x;
    if (idx >= 128 * 64) return;
    int r = idx >> 6, c = idx & 63;
    float acc = 0.f;
#pragma unroll
    for (int k = 0; k < 64; ++k) acc += W1[r * 64 + k] * W2[k * 64 + c];
    W12[idx] = acc;
}

__global__ void k_wc(const float* __restrict__ W12, const float* __restrict__ W3,
                     float* __restrict__ Wc) {
    int idx = blockIdx.x * blockDim.x + threadIdx.x;
    if (idx >= 128 * 40) return;
    int r = idx / 40, c = idx - r * 40;
    float acc = 0.f;
#pragma unroll
    for (int k = 0; k < 64; ++k) acc += W12[r * 64 + k] * W3[k * 40 + c];
    Wc[idx] = acc;
}

// ---------- y0 = x(N x 128) @ Wc(128x40) ----------
__global__ void k_gemm(const float4* __restrict__ x4, const float4* __restrict__ Wc4,
                       float4* __restrict__ y4, int n_nodes) {
    __shared__ float4 wc[128 * 10];
    for (int i = threadIdx.x; i < 1280; i += blockDim.x) wc[i] = Wc4[i];
    __syncthreads();
    int tid = blockIdx.x * blockDim.x + threadIdx.x;
    int node = tid / 5, j0 = tid - node * 5;
    if (node >= n_nodes) return;
    float4 a0 = {0.f, 0.f, 0.f, 0.f}, a1 = {0.f, 0.f, 0.f, 0.f};
    const float4* xr = x4 + (size_t)node * 32;
#pragma unroll
    for (int k4 = 0; k4 < 32; ++k4) {
        float4 v = xr[k4];
#pragma unroll
        for (int kk = 0; kk < 4; ++kk) {
            float c = (kk == 0) ? v.x : (kk == 1) ? v.y : (kk == 2) ? v.z : v.w;
            float4 w0 = wc[(k4 * 4 + kk) * 10 + j0 * 2];
            float4 w1 = wc[(k4 * 4 + kk) * 10 + j0 * 2 + 1];
            a0.x += c * w0.x; a0.y += c * w0.y; a0.z += c * w0.z; a0.w += c * w0.w;
            a1.x += c * w1.x; a1.y += c * w1.y; a1.z += c * w1.z; a1.w += c * w1.w;
        }
    }
    y4[(size_t)node * 10 + j0 * 2]     = a0;
    y4[(size_t)node * 10 + j0 * 2 + 1] = a1;
}

// ---------- bucket histogram (LDS-aggregated) ----------
__global__ void k_bhist(const int* __restrict__ dst, int* __restrict__ gcnt,
                        int E, int nb) {
    __shared__ int h[NBMAX];
    for (int i = threadIdx.x; i < nb; i += blockDim.x) h[i] = 0;
    __syncthreads();
    for (int e = blockIdx.x * blockDim.x + threadIdx.x; e < E;
         e += gridDim.x * blockDim.x)
        atomicAdd(&h[dst[e] >> 7], 1);
    __syncthreads();
    for (int i = threadIdx.x; i < nb; i += blockDim.x)
        if (h[i]) atomicAdd(&gcnt[i], h[i]);
}

// ---------- single-block scan over <=1024 buckets ----------
__global__ void k_bscan(const int* __restrict__ gcnt, int* __restrict__ boffs,
                        int* __restrict__ gcur, int nb) {
    __shared__ int sh[NBMAX];
    int t = threadIdx.x;
    int v0 = (t < nb) ? gcnt[t] : 0;
    sh[t] = v0;
    __syncthreads();
    for (int off = 1; off < NBMAX; off <<= 1) {
        int v = (t >= off) ? sh[t - off] : 0;
        __syncthreads();
        sh[t] += v;
        __syncthreads();
    }
    int exc = sh[t] - v0;
    if (t < nb) { boffs[t] = exc; gcur[t] = exc; }
    if (t == nb - 1) boffs[nb] = sh[t];
}

// ---------- partition edges into buckets, packed (src<<7)|(dst&127) ----------
#define PCHUNK 8192
__global__ void k_part(const int* __restrict__ src, const int* __restrict__ dst,
                       int* __restrict__ gcur, int* __restrict__ part,
                       int E, int nb) {
    __shared__ int h[NBMAX];
    __shared__ int base[NBMAX];
    int t = threadIdx.x;
    int e0 = blockIdx.x * PCHUNK;
    int e1 = min(e0 + PCHUNK, E);
    for (int i = t; i < nb; i += 256) h[i] = 0;
    __syncthreads();
    for (int e = e0 + t; e < e1; e += 256)
        atomicAdd(&h[dst[e] >> 7], 1);
    __syncthreads();
    for (int i = t; i < nb; i += 256) {
        int c = h[i];
        base[i] = c ? atomicAdd(&gcur[i], c) : 0;
    }
    __syncthreads();
    for (int i = t; i < nb; i += 256) h[i] = 0;   // reuse as local cursor
    __syncthreads();
    for (int e = e0 + t; e < e1; e += 256) {
        int d = dst[e];
        int b = d >> 7;
        int p = base[b] + atomicAdd(&h[b], 1);
        part[p] = (src[e] << 7) | (d & 127);
    }
}

// ---------- bucket aggregation: LDS tile accumulate ----------
template <int FINAL>
__global__ void k_bagg(const float* __restrict__ yin, float* __restrict__ yout,
                       const int* __restrict__ boffs, const int* __restrict__ part,
                       int N) {
    __shared__ float tile[BW * D];          // 20480 B
    int b = blockIdx.x;
    int t = threadIdx.x;                    // 512 threads, 8 waves
    for (int i = t; i < BW * D; i += 512) tile[i] = 0.f;
    __syncthreads();
    int beg = boffs[b], end = boffs[b + 1];
    int w = t >> 6, lane = t & 63;
    int k = beg + w;
    for (; k + 24 < end; k += 32) {
        int p0 = part[k], p1 = part[k + 8], p2 = part[k + 16], p3 = part[k + 24];
        if (lane < D) {
            float v0 = yin[(p0 >> 7) * D + lane];
            float v1 = yin[(p1 >> 7) * D + lane];
            float v2 = yin[(p2 >> 7) * D + lane];
            float v3 = yin[(p3 >> 7) * D + lane];
            atomicAdd(&tile[(p0 & 127) * D + lane], v0);
            atomicAdd(&tile[(p1 & 127) * D + lane], v1);
            atomicAdd(&tile[(p2 & 127) * D + lane], v2);
            atomicAdd(&tile[(p3 & 127) * D + lane], v3);
        }
    }
    for (; k < end; k += 8) {
        int p0 = part[k];
        if (lane < D)
            atomicAdd(&tile[(p0 & 127) * D + lane], yin[(p0 >> 7) * D + lane]);
    }
    __syncthreads();
    int node0 = b * BW;
    int rows = min(BW, N - node0);
    if (FINAL) {
        for (int r = w; r < rows; r += 8) {
            float acc = (lane < D) ? tile[r * D + lane] : 0.f;
            float mv = (lane < D) ? acc : -INFINITY;
#pragma unroll
            for (int off = 32; off; off >>= 1) mv = fmaxf(mv, __shfl_xor(mv, off, 64));
            float ev = (lane < D) ? __expf(acc - mv) : 0.f;
#pragma unroll
            for (int off = 32; off; off >>= 1) ev += __shfl_xor(ev, off, 64);
            float ls = __logf(ev);
            if (lane < D) yout[(size_t)(node0 + r) * D + lane] = acc - mv - ls;
        }
    } else {
        int nf4 = rows * D / 4;
        const float4* t4 = (const float4*)tile;
        float4* o4 = (float4*)(yout + (size_t)node0 * D);
        for (int i = t; i < nf4; i += 512) o4[i] = t4[i];
    }
}

extern "C" void kernel_launch(void* const* d_in, const int* in_sizes, int n_in,
                              void* d_out, int out_size, void* d_ws, size_t ws_size,
                              hipStream_t stream) {
    const float* x   = (const float*)d_in[0];
    const int* esrc  = (const int*)d_in[1];
    const int* edst  = (const int*)d_in[2];
    const float* W1  = (const float*)d_in[3];
    const float* W2  = (const float*)d_in[4];
    const float* W3  = (const float*)d_in[5];
    int N = in_sizes[0] / 128;
    int E = in_sizes[1];
    float* out = (float*)d_out;

    char* ws = (char*)d_ws;
    auto alloc = [&](size_t bytes) {
        char* p = ws;
        ws += (bytes + 255) & ~(size_t)255;
        return p;
    };
    float* bufA  = (float*)alloc((size_t)N * D * sizeof(float));
    float* bufB  = (float*)alloc((size_t)N * D * sizeof(float));
    float* W12   = (float*)alloc(128 * 64 * sizeof(float));
    float* Wc    = (float*)alloc(128 * 40 * sizeof(float));
    int* gcnt    = (int*)alloc(NBMAX * sizeof(int));
    int* boffs   = (int*)alloc((NBMAX + 1) * sizeof(int));
    int* gcur    = (int*)alloc(NBMAX * sizeof(int));
    int* part    = (int*)alloc((size_t)E * sizeof(int));

    int nb = (N + BW - 1) / BW;

    hipMemsetAsync(gcnt, 0, NBMAX * sizeof(int), stream);

    k_w12<<<(128 * 64 + 255) / 256, 256, 0, stream>>>(W1, W2, W12);
    k_wc<<<(128 * 40 + 255) / 256, 256, 0, stream>>>(W12, W3, Wc);
    k_gemm<<<(N * 5 + 255) / 256, 256, 0, stream>>>((const float4*)x, (const float4*)Wc,
                                                    (float4*)bufA, N);

    k_bhist<<<512, 256, 0, stream>>>(edst, gcnt, E, nb);
    k_bscan<<<1, NBMAX, 0, stream>>>(gcnt, boffs, gcur, nb);
    k_part<<<(E + PCHUNK - 1) / PCHUNK, 256, 0, stream>>>(esrc, edst, gcur, part, E, nb);

    k_bagg<0><<<nb, 512, 0, stream>>>(bufA, bufB, boffs, part, N);
    k_bagg<0><<<nb, 512, 0, stream>>>(bufB, bufA, boffs, part, N);
    k_bagg<1><<<nb, 512, 0, stream>>>(bufA, out, boffs, part, N);
}

// Round 4
// 289.999 us; speedup vs baseline: 4.7419x; 4.7419x over previous
//
#include <hip/hip_runtime.h>
#include <math.h>

// SGC: out = log_softmax( S^3 * x * (W1*W2*W3) )
// Pipeline: collapse weights -> dense GEMM (f32 in, bf16 out, 128B rows)
// -> bucket partition -> bucket-local exact CSR -> 3x wave-per-node gather-agg.

#define BW    128     // nodes per bucket
#define NBMAX 1024
#define D     40
#define RS    64      // padded row stride (bf16 elems) = 128 B

typedef unsigned short u16;
typedef unsigned int   u32;

static __device__ inline u16 f2bf(float f) {
    u32 u = __float_as_uint(f);
    u32 r = (u + 0x7FFF + ((u >> 16) & 1)) >> 16;
    return (u16)r;
}
static __device__ inline float bf2f(u16 v) {
    return __uint_as_float(((u32)v) << 16);
}
static __device__ inline u32 pack2(float lo, float hi) {
    return (u32)f2bf(lo) | ((u32)f2bf(hi) << 16);
}

// ---------- tiny weight-collapse GEMMs ----------
__global__ void k_w12(const float* __restrict__ W1, const float* __restrict__ W2,
                      float* __restrict__ W12) {
    int idx = blockIdx.x * blockDim.x + threadIdx.x;
    if (idx >= 128 * 64) return;
    int r = idx >> 6, c = idx & 63;
    float acc = 0.f;
#pragma unroll
    for (int k = 0; k < 64; ++k) acc += W1[r * 64 + k] * W2[k * 64 + c];
    W12[idx] = acc;
}

__global__ void k_wc(const float* __restrict__ W12, const float* __restrict__ W3,
                     float* __restrict__ Wc) {
    int idx = blockIdx.x * blockDim.x + threadIdx.x;
    if (idx >= 128 * 40) return;
    int r = idx / 40, c = idx - r * 40;
    float acc = 0.f;
#pragma unroll
    for (int k = 0; k < 64; ++k) acc += W12[r * 64 + k] * W3[k * 40 + c];
    Wc[idx] = acc;
}

// ---------- y0 = x(N x 128) @ Wc(128x40), bf16 out, row stride RS ----------
__global__ void k_gemm(const float4* __restrict__ x4, const float4* __restrict__ Wc4,
                       u16* __restrict__ yout, int n_nodes) {
    __shared__ float4 wc[128 * 10];
    for (int i = threadIdx.x; i < 1280; i += blockDim.x) wc[i] = Wc4[i];
    __syncthreads();
    int tid = blockIdx.x * blockDim.x + threadIdx.x;
    int node = tid / 5, j0 = tid - node * 5;
    if (node >= n_nodes) return;
    float4 a0 = {0.f, 0.f, 0.f, 0.f}, a1 = {0.f, 0.f, 0.f, 0.f};
    const float4* xr = x4 + (size_t)node * 32;
#pragma unroll
    for (int k4 = 0; k4 < 32; ++k4) {
        float4 v = xr[k4];
#pragma unroll
        for (int kk = 0; kk < 4; ++kk) {
            float c = (kk == 0) ? v.x : (kk == 1) ? v.y : (kk == 2) ? v.z : v.w;
            float4 w0 = wc[(k4 * 4 + kk) * 10 + j0 * 2];
            float4 w1 = wc[(k4 * 4 + kk) * 10 + j0 * 2 + 1];
            a0.x += c * w0.x; a0.y += c * w0.y; a0.z += c * w0.z; a0.w += c * w0.w;
            a1.x += c * w1.x; a1.y += c * w1.y; a1.z += c * w1.z; a1.w += c * w1.w;
        }
    }
    uint4 st;
    st.x = pack2(a0.x, a0.y); st.y = pack2(a0.z, a0.w);
    st.z = pack2(a1.x, a1.y); st.w = pack2(a1.z, a1.w);
    *(uint4*)(yout + (size_t)node * RS + j0 * 8) = st;
}

// ---------- bucket histogram ----------
__global__ void k_bhist(const int* __restrict__ dst, int* __restrict__ gcnt,
                        int E, int nb) {
    __shared__ int h[NBMAX];
    for (int i = threadIdx.x; i < nb; i += blockDim.x) h[i] = 0;
    __syncthreads();
    for (int e = blockIdx.x * blockDim.x + threadIdx.x; e < E;
         e += gridDim.x * blockDim.x)
        atomicAdd(&h[dst[e] >> 7], 1);
    __syncthreads();
    for (int i = threadIdx.x; i < nb; i += blockDim.x)
        if (h[i]) atomicAdd(&gcnt[i], h[i]);
}

// ---------- single-block scan over <=1024 buckets ----------
__global__ void k_bscan(const int* __restrict__ gcnt, int* __restrict__ boffs,
                        int* __restrict__ gcur, int nb) {
    __shared__ int sh[NBMAX];
    int t = threadIdx.x;
    int v0 = (t < nb) ? gcnt[t] : 0;
    sh[t] = v0;
    __syncthreads();
    for (int off = 1; off < NBMAX; off <<= 1) {
        int v = (t >= off) ? sh[t - off] : 0;
        __syncthreads();
        sh[t] += v;
        __syncthreads();
    }
    int exc = sh[t] - v0;
    if (t < nb) { boffs[t] = exc; gcur[t] = exc; }
    if (t == nb - 1) boffs[nb] = sh[t];
}

// ---------- partition edges into buckets, packed (src<<7)|(dst&127) ----------
#define PCHUNK 8192
__global__ void k_part(const int* __restrict__ src, const int* __restrict__ dst,
                       int* __restrict__ gcur, int* __restrict__ part,
                       int E, int nb) {
    __shared__ int h[NBMAX];
    __shared__ int base[NBMAX];
    int t = threadIdx.x;
    int e0 = blockIdx.x * PCHUNK;
    int e1 = min(e0 + PCHUNK, E);
    for (int i = t; i < nb; i += 256) h[i] = 0;
    __syncthreads();
    for (int e = e0 + t; e < e1; e += 256)
        atomicAdd(&h[dst[e] >> 7], 1);
    __syncthreads();
    for (int i = t; i < nb; i += 256) {
        int c = h[i];
        base[i] = c ? atomicAdd(&gcur[i], c) : 0;
    }
    __syncthreads();
    for (int i = t; i < nb; i += 256) h[i] = 0;   // reuse as local cursor
    __syncthreads();
    for (int e = e0 + t; e < e1; e += 256) {
        int d = dst[e];
        int b = d >> 7;
        int p = base[b] + atomicAdd(&h[b], 1);
        part[p] = (src[e] << 7) | (d & 127);
    }
}

// ---------- bucket-local exact CSR: offs[node], ssort (src sorted by dst) ----
__global__ void k_csr(const int* __restrict__ part, const int* __restrict__ boffs,
                      int* __restrict__ offs, int* __restrict__ ssort, int N) {
    __shared__ int cnt[BW];
    __shared__ int pos[BW];
    __shared__ int cur[BW];
    __shared__ int wsum[2];
    int b = blockIdx.x, t = threadIdx.x;
    int beg = boffs[b], end = boffs[b + 1];
    if (t < BW) cnt[t] = 0;
    __syncthreads();
    for (int k = beg + t; k < end; k += 256)
        atomicAdd(&cnt[part[k] & 127], 1);
    __syncthreads();
    int v = 0, inc = 0;
    if (t < BW) {
        v = cnt[t];
        inc = v;
#pragma unroll
        for (int off = 1; off < 64; off <<= 1) {
            int u = __shfl_up(inc, off, 64);
            if ((t & 63) >= off) inc += u;
        }
        if ((t & 63) == 63) wsum[t >> 6] = inc;
    }
    __syncthreads();
    int node0 = b * BW;
    if (t < BW) {
        int base = beg + ((t >= 64) ? wsum[0] : 0) + inc - v;  // exclusive
        pos[t] = base;
        cur[t] = 0;
        if (node0 + t < N) offs[node0 + t] = base;
    }
    if (b == gridDim.x - 1 && t == 0) offs[N] = end;
    __syncthreads();
    for (int k = beg + t; k < end; k += 256) {
        int p = part[k];
        int r = p & 127;
        int loc = atomicAdd(&cur[r], 1);
        ssort[pos[r] + loc] = p >> 7;
    }
}

// ---------- aggregation: wave per node, bf16 gather, f32 accumulate ----------
template <int FINAL>
__global__ void k_agg(const u16* __restrict__ yin, void* __restrict__ youtv,
                      const int* __restrict__ offs, const int* __restrict__ srcs,
                      int n_nodes) {
    int wid = (blockIdx.x * blockDim.x + threadIdx.x) >> 6;
    int lane = threadIdx.x & 63;
    if (wid >= n_nodes) return;
    int beg = offs[wid], end = offs[wid + 1];
    float a0 = 0.f, a1 = 0.f, a2 = 0.f, a3 = 0.f;
    if (lane < D) {
        int k = beg;
        for (; k + 8 <= end; k += 8) {
            int s0 = srcs[k],     s1 = srcs[k + 1], s2 = srcs[k + 2], s3 = srcs[k + 3];
            int s4 = srcs[k + 4], s5 = srcs[k + 5], s6 = srcs[k + 6], s7 = srcs[k + 7];
            float v0 = bf2f(yin[(size_t)s0 * RS + lane]);
            float v1 = bf2f(yin[(size_t)s1 * RS + lane]);
            float v2 = bf2f(yin[(size_t)s2 * RS + lane]);
            float v3 = bf2f(yin[(size_t)s3 * RS + lane]);
            float v4 = bf2f(yin[(size_t)s4 * RS + lane]);
            float v5 = bf2f(yin[(size_t)s5 * RS + lane]);
            float v6 = bf2f(yin[(size_t)s6 * RS + lane]);
            float v7 = bf2f(yin[(size_t)s7 * RS + lane]);
            a0 += v0; a1 += v1; a2 += v2; a3 += v3;
            a0 += v4; a1 += v5; a2 += v6; a3 += v7;
        }
        for (; k < end; ++k) a0 += bf2f(yin[(size_t)srcs[k] * RS + lane]);
    }
    float acc = (a0 + a1) + (a2 + a3);
    if (FINAL) {
        float mv = (lane < D) ? acc : -INFINITY;
#pragma unroll
        for (int off = 32; off; off >>= 1) mv = fmaxf(mv, __shfl_xor(mv, off, 64));
        float ev = (lane < D) ? __expf(acc - mv) : 0.f;
#pragma unroll
        for (int off = 32; off; off >>= 1) ev += __shfl_xor(ev, off, 64);
        float ls = __logf(ev);
        if (lane < D) ((float*)youtv)[(size_t)wid * D + lane] = acc - mv - ls;
    } else {
        if (lane < D) ((u16*)youtv)[(size_t)wid * RS + lane] = f2bf(acc);
    }
}

extern "C" void kernel_launch(void* const* d_in, const int* in_sizes, int n_in,
                              void* d_out, int out_size, void* d_ws, size_t ws_size,
                              hipStream_t stream) {
    const float* x   = (const float*)d_in[0];
    const int* esrc  = (const int*)d_in[1];
    const int* edst  = (const int*)d_in[2];
    const float* W1  = (const float*)d_in[3];
    const float* W2  = (const float*)d_in[4];
    const float* W3  = (const float*)d_in[5];
    int N = in_sizes[0] / 128;
    int E = in_sizes[1];
    float* out = (float*)d_out;

    char* ws = (char*)d_ws;
    auto alloc = [&](size_t bytes) {
        char* p = ws;
        ws += (bytes + 255) & ~(size_t)255;
        return p;
    };
    u16* bufA   = (u16*)alloc((size_t)N * RS * sizeof(u16));   // 12.8 MB
    u16* bufB   = (u16*)alloc((size_t)N * RS * sizeof(u16));   // 12.8 MB
    int* part   = (int*)bufB;  // alias: part dead before bufB first written
    int* ssort  = (int*)alloc((size_t)E * sizeof(int));        // 6.4 MB
    int* offs   = (int*)alloc((size_t)(N + 1) * sizeof(int));
    float* W12  = (float*)alloc(128 * 64 * sizeof(float));
    float* Wc   = (float*)alloc(128 * 40 * sizeof(float));
    int* gcnt   = (int*)alloc(NBMAX * sizeof(int));
    int* boffs  = (int*)alloc((NBMAX + 1) * sizeof(int));
    int* gcur   = (int*)alloc(NBMAX * sizeof(int));

    int nb = (N + BW - 1) / BW;

    hipMemsetAsync(gcnt, 0, NBMAX * sizeof(int), stream);

    k_w12<<<(128 * 64 + 255) / 256, 256, 0, stream>>>(W1, W2, W12);
    k_wc<<<(128 * 40 + 255) / 256, 256, 0, stream>>>(W12, W3, Wc);
    k_gemm<<<(N * 5 + 255) / 256, 256, 0, stream>>>((const float4*)x, (const float4*)Wc,
                                                    bufA, N);

    k_bhist<<<512, 256, 0, stream>>>(edst, gcnt, E, nb);
    k_bscan<<<1, NBMAX, 0, stream>>>(gcnt, boffs, gcur, nb);
    k_part<<<(E + PCHUNK - 1) / PCHUNK, 256, 0, stream>>>(esrc, edst, gcur, part, E, nb);
    k_csr<<<nb, 256, 0, stream>>>(part, boffs, offs, ssort, N);

    int agg_grid = (N * 64 + 255) / 256;
    k_agg<0><<<agg_grid, 256, 0, stream>>>(bufA, bufB, offs, ssort, N);
    k_agg<0><<<agg_grid, 256, 0, stream>>>(bufB, bufA, offs, ssort, N);
    k_agg<1><<<agg_grid, 256, 0, stream>>>(bufA, out, offs, ssort, N);
}

// Round 5
// 241.590 us; speedup vs baseline: 5.6920x; 1.2004x over previous
//
#include <hip/hip_runtime.h>
#include <math.h>

// SGC: out = log_softmax( S^3 * x * (W1*W2*W3) )
// Pipeline: collapse weights -> dense GEMM (f32 in, bf16 out, 128B rows)
// -> bucket partition -> bucket-local exact CSR -> 3x wave-per-node gather-agg.
// k_agg: packed gather — 10 lanes x uint2 (4 bf16) per row, 6 edges per wave-iter.

#define BW    128     // nodes per bucket
#define NBMAX 1024
#define D     40
#define RS    64      // padded row stride (bf16 elems) = 128 B

typedef unsigned short u16;
typedef unsigned int   u32;

static __device__ inline u16 f2bf(float f) {
    u32 u = __float_as_uint(f);
    u32 r = (u + 0x7FFF + ((u >> 16) & 1)) >> 16;
    return (u16)r;
}
static __device__ inline u32 pack2(float lo, float hi) {
    return (u32)f2bf(lo) | ((u32)f2bf(hi) << 16);
}

// ---------- tiny weight-collapse GEMMs ----------
__global__ void k_w12(const float* __restrict__ W1, const float* __restrict__ W2,
                      float* __restrict__ W12) {
    int idx = blockIdx.x * blockDim.x + threadIdx.x;
    if (idx >= 128 * 64) return;
    int r = idx >> 6, c = idx & 63;
    float acc = 0.f;
#pragma unroll
    for (int k = 0; k < 64; ++k) acc += W1[r * 64 + k] * W2[k * 64 + c];
    W12[idx] = acc;
}

__global__ void k_wc(const float* __restrict__ W12, const float* __restrict__ W3,
                     float* __restrict__ Wc) {
    int idx = blockIdx.x * blockDim.x + threadIdx.x;
    if (idx >= 128 * 40) return;
    int r = idx / 40, c = idx - r * 40;
    float acc = 0.f;
#pragma unroll
    for (int k = 0; k < 64; ++k) acc += W12[r * 64 + k] * W3[k * 40 + c];
    Wc[idx] = acc;
}

// ---------- y0 = x(N x 128) @ Wc(128x40), bf16 out, row stride RS ----------
__global__ void k_gemm(const float4* __restrict__ x4, const float4* __restrict__ Wc4,
                       u16* __restrict__ yout, int n_nodes) {
    __shared__ float4 wc[128 * 10];
    for (int i = threadIdx.x; i < 1280; i += blockDim.x) wc[i] = Wc4[i];
    __syncthreads();
    int tid = blockIdx.x * blockDim.x + threadIdx.x;
    int node = tid / 5, j0 = tid - node * 5;
    if (node >= n_nodes) return;
    float4 a0 = {0.f, 0.f, 0.f, 0.f}, a1 = {0.f, 0.f, 0.f, 0.f};
    const float4* xr = x4 + (size_t)node * 32;
#pragma unroll
    for (int k4 = 0; k4 < 32; ++k4) {
        float4 v = xr[k4];
#pragma unroll
        for (int kk = 0; kk < 4; ++kk) {
            float c = (kk == 0) ? v.x : (kk == 1) ? v.y : (kk == 2) ? v.z : v.w;
            float4 w0 = wc[(k4 * 4 + kk) * 10 + j0 * 2];
            float4 w1 = wc[(k4 * 4 + kk) * 10 + j0 * 2 + 1];
            a0.x += c * w0.x; a0.y += c * w0.y; a0.z += c * w0.z; a0.w += c * w0.w;
            a1.x += c * w1.x; a1.y += c * w1.y; a1.z += c * w1.z; a1.w += c * w1.w;
        }
    }
    uint4 st;
    st.x = pack2(a0.x, a0.y); st.y = pack2(a0.z, a0.w);
    st.z = pack2(a1.x, a1.y); st.w = pack2(a1.z, a1.w);
    *(uint4*)(yout + (size_t)node * RS + j0 * 8) = st;
}

// ---------- bucket histogram ----------
__global__ void k_bhist(const int* __restrict__ dst, int* __restrict__ gcnt,
                        int E, int nb) {
    __shared__ int h[NBMAX];
    for (int i = threadIdx.x; i < nb; i += blockDim.x) h[i] = 0;
    __syncthreads();
    for (int e = blockIdx.x * blockDim.x + threadIdx.x; e < E;
         e += gridDim.x * blockDim.x)
        atomicAdd(&h[dst[e] >> 7], 1);
    __syncthreads();
    for (int i = threadIdx.x; i < nb; i += blockDim.x)
        if (h[i]) atomicAdd(&gcnt[i], h[i]);
}

// ---------- single-block scan over <=1024 buckets ----------
__global__ void k_bscan(const int* __restrict__ gcnt, int* __restrict__ boffs,
                        int* __restrict__ gcur, int nb) {
    __shared__ int sh[NBMAX];
    int t = threadIdx.x;
    int v0 = (t < nb) ? gcnt[t] : 0;
    sh[t] = v0;
    __syncthreads();
    for (int off = 1; off < NBMAX; off <<= 1) {
        int v = (t >= off) ? sh[t - off] : 0;
        __syncthreads();
        sh[t] += v;
        __syncthreads();
    }
    int exc = sh[t] - v0;
    if (t < nb) { boffs[t] = exc; gcur[t] = exc; }
    if (t == nb - 1) boffs[nb] = sh[t];
}

// ---------- partition edges into buckets, packed (src<<7)|(dst&127) ----------
#define PCHUNK 8192
__global__ void k_part(const int* __restrict__ src, const int* __restrict__ dst,
                       int* __restrict__ gcur, int* __restrict__ part,
                       int E, int nb) {
    __shared__ int h[NBMAX];
    __shared__ int base[NBMAX];
    int t = threadIdx.x;
    int e0 = blockIdx.x * PCHUNK;
    int e1 = min(e0 + PCHUNK, E);
    for (int i = t; i < nb; i += 256) h[i] = 0;
    __syncthreads();
    for (int e = e0 + t; e < e1; e += 256)
        atomicAdd(&h[dst[e] >> 7], 1);
    __syncthreads();
    for (int i = t; i < nb; i += 256) {
        int c = h[i];
        base[i] = c ? atomicAdd(&gcur[i], c) : 0;
    }
    __syncthreads();
    for (int i = t; i < nb; i += 256) h[i] = 0;   // reuse as local cursor
    __syncthreads();
    for (int e = e0 + t; e < e1; e += 256) {
        int d = dst[e];
        int b = d >> 7;
        int p = base[b] + atomicAdd(&h[b], 1);
        part[p] = (src[e] << 7) | (d & 127);
    }
}

// ---------- bucket-local exact CSR: offs[node], ssort (src sorted by dst) ----
__global__ void k_csr(const int* __restrict__ part, const int* __restrict__ boffs,
                      int* __restrict__ offs, int* __restrict__ ssort, int N) {
    __shared__ int cnt[BW];
    __shared__ int pos[BW];
    __shared__ int cur[BW];
    __shared__ int wsum[2];
    int b = blockIdx.x, t = threadIdx.x;
    int beg = boffs[b], end = boffs[b + 1];
    if (t < BW) cnt[t] = 0;
    __syncthreads();
    for (int k = beg + t; k < end; k += 256)
        atomicAdd(&cnt[part[k] & 127], 1);
    __syncthreads();
    int v = 0, inc = 0;
    if (t < BW) {
        v = cnt[t];
        inc = v;
#pragma unroll
        for (int off = 1; off < 64; off <<= 1) {
            int u = __shfl_up(inc, off, 64);
            if ((t & 63) >= off) inc += u;
        }
        if ((t & 63) == 63) wsum[t >> 6] = inc;
    }
    __syncthreads();
    int node0 = b * BW;
    if (t < BW) {
        int base = beg + ((t >= 64) ? wsum[0] : 0) + inc - v;  // exclusive
        pos[t] = base;
        cur[t] = 0;
        if (node0 + t < N) offs[node0 + t] = base;
    }
    if (b == gridDim.x - 1 && t == 0) offs[N] = end;
    __syncthreads();
    for (int k = beg + t; k < end; k += 256) {
        int p = part[k];
        int r = p & 127;
        int loc = atomicAdd(&cur[r], 1);
        ssort[pos[r] + loc] = p >> 7;
    }
}

// ---------- aggregation: wave per node, packed gather ----------
// 6 groups of 10 lanes; group g handles edge k+g; each lane loads uint2
// (4 bf16 features). Fold groups at the end; lanes 0..9 hold the 40 sums.
template <int FINAL>
__global__ void k_agg(const u16* __restrict__ yin, void* __restrict__ youtv,
                      const int* __restrict__ offs, const int* __restrict__ srcs,
                      int n_nodes) {
    int wid = (blockIdx.x * blockDim.x + threadIdx.x) >> 6;
    int lane = threadIdx.x & 63;
    if (wid >= n_nodes) return;
    int beg = offs[wid], end = offs[wid + 1];
    int g = lane / 10;            // 0..6 (lanes 60..63 idle)
    int sub = lane - g * 10;      // 0..9
    bool act = (g < 6);
    const char* base = (const char*)yin + sub * 8;
    float a0 = 0.f, a1 = 0.f, a2 = 0.f, a3 = 0.f;
    for (int k = beg; k < end; k += 12) {
        int e0 = k + g, e1 = k + 6 + g;
        if (act && e0 < end) {
            uint2 w = *(const uint2*)(base + (size_t)((u32)srcs[e0] * 128u));
            a0 += __uint_as_float(w.x << 16);
            a1 += __uint_as_float(w.x & 0xFFFF0000u);
            a2 += __uint_as_float(w.y << 16);
            a3 += __uint_as_float(w.y & 0xFFFF0000u);
        }
        if (act && e1 < end) {
            uint2 w = *(const uint2*)(base + (size_t)((u32)srcs[e1] * 128u));
            a0 += __uint_as_float(w.x << 16);
            a1 += __uint_as_float(w.x & 0xFFFF0000u);
            a2 += __uint_as_float(w.y << 16);
            a3 += __uint_as_float(w.y & 0xFFFF0000u);
        }
    }
    // fold 6 groups -> lanes 0..9 (tree: +30, then +10/+20; shfls read
    // the unmodified source register at each step)
    float b0 = a0 + __shfl(a0, lane + 30, 64);
    float b1 = a1 + __shfl(a1, lane + 30, 64);
    float b2 = a2 + __shfl(a2, lane + 30, 64);
    float b3 = a3 + __shfl(a3, lane + 30, 64);
    float s0 = b0 + __shfl(b0, lane + 10, 64) + __shfl(b0, lane + 20, 64);
    float s1 = b1 + __shfl(b1, lane + 10, 64) + __shfl(b1, lane + 20, 64);
    float s2 = b2 + __shfl(b2, lane + 10, 64) + __shfl(b2, lane + 20, 64);
    float s3 = b3 + __shfl(b3, lane + 10, 64) + __shfl(b3, lane + 20, 64);
    if (FINAL) {
        float m = fmaxf(fmaxf(s0, s1), fmaxf(s2, s3));
        float mv = (lane < 10) ? m : -INFINITY;
#pragma unroll
        for (int off = 8; off; off >>= 1) mv = fmaxf(mv, __shfl_xor(mv, off, 16));
        float ev = 0.f;
        if (lane < 10)
            ev = __expf(s0 - mv) + __expf(s1 - mv) + __expf(s2 - mv) + __expf(s3 - mv);
#pragma unroll
        for (int off = 8; off; off >>= 1) ev += __shfl_xor(ev, off, 16);
        float ls = __logf(ev);
        if (lane < 10) {
            float4 o = {s0 - mv - ls, s1 - mv - ls, s2 - mv - ls, s3 - mv - ls};
            ((float4*)((float*)youtv + (size_t)wid * D))[sub] = o;
        }
    } else {
        if (lane < 10) {
            uint2 st = {pack2(s0, s1), pack2(s2, s3)};
            *(uint2*)((u16*)youtv + (size_t)wid * RS + sub * 4) = st;
        }
    }
}

extern "C" void kernel_launch(void* const* d_in, const int* in_sizes, int n_in,
                              void* d_out, int out_size, void* d_ws, size_t ws_size,
                              hipStream_t stream) {
    const float* x   = (const float*)d_in[0];
    const int* esrc  = (const int*)d_in[1];
    const int* edst  = (const int*)d_in[2];
    const float* W1  = (const float*)d_in[3];
    const float* W2  = (const float*)d_in[4];
    const float* W3  = (const float*)d_in[5];
    int N = in_sizes[0] / 128;
    int E = in_sizes[1];
    float* out = (float*)d_out;

    char* ws = (char*)d_ws;
    auto alloc = [&](size_t bytes) {
        char* p = ws;
        ws += (bytes + 255) & ~(size_t)255;
        return p;
    };
    u16* bufA   = (u16*)alloc((size_t)N * RS * sizeof(u16));   // 12.8 MB
    u16* bufB   = (u16*)alloc((size_t)N * RS * sizeof(u16));   // 12.8 MB
    int* part   = (int*)bufB;  // alias: part dead before bufB first written
    int* ssort  = (int*)alloc((size_t)E * sizeof(int));        // 6.4 MB
    int* offs   = (int*)alloc((size_t)(N + 1) * sizeof(int));
    float* W12  = (float*)alloc(128 * 64 * sizeof(float));
    float* Wc   = (float*)alloc(128 * 40 * sizeof(float));
    int* gcnt   = (int*)alloc(NBMAX * sizeof(int));
    int* boffs  = (int*)alloc((NBMAX + 1) * sizeof(int));
    int* gcur   = (int*)alloc(NBMAX * sizeof(int));

    int nb = (N + BW - 1) / BW;

    hipMemsetAsync(gcnt, 0, NBMAX * sizeof(int), stream);

    k_w12<<<(128 * 64 + 255) / 256, 256, 0, stream>>>(W1, W2, W12);
    k_wc<<<(128 * 40 + 255) / 256, 256, 0, stream>>>(W12, W3, Wc);
    k_gemm<<<(N * 5 + 255) / 256, 256, 0, stream>>>((const float4*)x, (const float4*)Wc,
                                                    bufA, N);

    k_bhist<<<512, 256, 0, stream>>>(edst, gcnt, E, nb);
    k_bscan<<<1, NBMAX, 0, stream>>>(gcnt, boffs, gcur, nb);
    k_part<<<(E + PCHUNK - 1) / PCHUNK, 256, 0, stream>>>(esrc, edst, gcur, part, E, nb);
    k_csr<<<nb, 256, 0, stream>>>(part, boffs, offs, ssort, N);

    int agg_grid = (N * 64 + 255) / 256;
    k_agg<0><<<agg_grid, 256, 0, stream>>>(bufA, bufB, offs, ssort, N);
    k_agg<0><<<agg_grid, 256, 0, stream>>>(bufB, bufA, offs, ssort, N);
    k_agg<1><<<agg_grid, 256, 0, stream>>>(bufA, out, offs, ssort, N);
}